// Round 8
// baseline (253.873 us; speedup 1.0000x reference)
//
#include <hip/hip_runtime.h>
#include <hip/hip_bf16.h>
#include <stdint.h>

// Problem constants
#define EXP 8
#define DIM 1024
#define SEQL 512
#define BATCH 8
#define OFF_AUX    4194304
#define OFF_MASK   4194305
#define OFF_LOGITS 4194369

typedef __bf16 bf16_t;
typedef bf16_t bf16x8 __attribute__((ext_vector_type(8)));
typedef bf16_t bf16x4 __attribute__((ext_vector_type(4)));
typedef float  f32x4  __attribute__((ext_vector_type(4)));

typedef __attribute__((address_space(1))) void* as1p;
typedef __attribute__((address_space(3))) void* as3p;

__device__ __forceinline__ void glds16(const void* g, void* l) {
  __builtin_amdgcn_global_load_lds((as1p)(void*)g, (as3p)l, 16, 0, 0);
}

#define CFENCE() asm volatile("" ::: "memory")
// s_waitcnt imms (gfx9 encoding: vm[3:0] | exp[6:4] | lgkm[11:8] | vm[5:4]<<14)
#define WAIT_VM8()  { CFENCE(); __builtin_amdgcn_s_waitcnt(0x0F78); CFENCE(); }  // vmcnt<=8
#define WAIT_VM0()  { CFENCE(); __builtin_amdgcn_s_waitcnt(0x0F70); CFENCE(); }  // vmcnt<=0
#define WAIT_LGKM() { CFENCE(); __builtin_amdgcn_s_waitcnt(0xC07F); CFENCE(); }  // lgkmcnt 0

// ---------------------------------------------------------------------------
// prep_kernel (r6): fused { w1+w2 transpose-cast 64x64 | x cast | router }.
// grid.x = 4096 + 512 + 1, 256 thr, 17.4 KB LDS.
// ---------------------------------------------------------------------------
__global__ __launch_bounds__(256) void prep_kernel(
    const float* __restrict__ x, const float* __restrict__ dec,
    const float* __restrict__ rw, const float* __restrict__ rb,
    const float* __restrict__ w1, const float* __restrict__ w2,
    bf16_t* __restrict__ xb, bf16_t* __restrict__ w1t, bf16_t* __restrict__ w2t,
    float* __restrict__ out_aux, float* __restrict__ out_mask,
    float* __restrict__ out_logits, int* __restrict__ idx_ws,
    float* __restrict__ w_ws) {
  __shared__ __align__(16) char smem[64 * 68 * 4];
  const int bid = blockIdx.x;
  const int t = threadIdx.x;

  if (bid < 4096) {
    const int z = bid >> 8;
    const int rem = bid & 255;
    const int k0 = (rem >> 4) * 64, n0 = (rem & 15) * 64;
    const float* src = (z < 8) ? (w1 + (size_t)z * DIM * DIM)
                               : (w2 + (size_t)(z - 8) * DIM * DIM);
    bf16_t* dst = (z < 8) ? (w1t + (size_t)z * DIM * DIM)
                          : (w2t + (size_t)(z - 8) * DIM * DIM);
    float (*tile)[68] = (float (*)[68])smem;
    const int r = t >> 4, c = t & 15;
    float4 v[4];
#pragma unroll
    for (int i = 0; i < 4; ++i)
      v[i] = *(const float4*)(src + (size_t)(k0 + r + 16 * i) * DIM + n0 + c * 4);
#pragma unroll
    for (int i = 0; i < 4; ++i)
      *(float4*)&tile[r + 16 * i][c * 4] = v[i];
    __syncthreads();
#pragma unroll
    for (int i2 = 0; i2 < 2; ++i2) {
      const int n = t & 63, kc = (t >> 6) + 4 * i2;
      bf16x8 o;
#pragma unroll
      for (int wd = 0; wd < 8; ++wd) o[wd] = (bf16_t)tile[kc * 8 + wd][n];
      *(bf16x8*)(dst + (size_t)(n0 + n) * DIM + k0 + kc * 8) = o;
    }
  } else if (bid < 4096 + 512) {
    const int i0 = (bid - 4096) * 2048 + t;
    float4 v[8];
#pragma unroll
    for (int i = 0; i < 8; ++i) v[i] = ((const float4*)x)[i0 + i * 256];
#pragma unroll
    for (int i = 0; i < 8; ++i) {
      bf16x4 o;
      o[0] = (bf16_t)v[i].x; o[1] = (bf16_t)v[i].y;
      o[2] = (bf16_t)v[i].z; o[3] = (bf16_t)v[i].w;
      ((bf16x4*)xb)[i0 + i * 256] = o;
    }
  } else {
    float* part  = (float*)smem;
    float* lg64  = part + 256;
    float* probs = lg64 + 64;
    float* msk   = probs + 64;
    const int p = t >> 2, seg = t & 3;
    const int b = p >> 3, e = p & 7;
    const float4* dv = (const float4*)(dec + b * DIM + seg * 256);
    const float4* wv = (const float4*)(rw + e * DIM + seg * 256);
    float s = 0.f;
#pragma unroll 8
    for (int i = 0; i < 64; ++i) {
      float4 a = dv[i], c = wv[i];
      s += a.x * c.x + a.y * c.y + a.z * c.z + a.w * c.w;
    }
    part[t] = s;
    __syncthreads();
    if (seg == 0) {
      float l = part[t] + part[t + 1] + part[t + 2] + part[t + 3] + rb[e];
      lg64[p] = l;
      out_logits[p] = l;
    }
    __syncthreads();
    if (t < 8) {
      float l[8];
      float mx = -1e30f;
#pragma unroll
      for (int k = 0; k < 8; ++k) { l[k] = lg64[t * 8 + k]; mx = fmaxf(mx, l[k]); }
      float pe[8];
      float sum = 0.f;
#pragma unroll
      for (int k = 0; k < 8; ++k) { pe[k] = expf(l[k] - mx); sum += pe[k]; }
      float inv = 1.f / sum;
#pragma unroll
      for (int k = 0; k < 8; ++k) { pe[k] *= inv; probs[t * 8 + k] = pe[k]; }
      int i0 = 0;
#pragma unroll
      for (int k = 1; k < 8; ++k) if (pe[k] > pe[i0]) i0 = k;
      int i1 = (i0 == 0) ? 1 : 0;
#pragma unroll
      for (int k = 0; k < 8; ++k) if (k != i0 && pe[k] > pe[i1]) i1 = k;
      float p0 = pe[i0], p1 = pe[i1];
      float invs = 1.f / (p0 + p1);
      idx_ws[t * 2] = i0;
      idx_ws[t * 2 + 1] = i1;
      w_ws[t * 2] = p0 * invs;
      w_ws[t * 2 + 1] = p1 * invs;
#pragma unroll
      for (int k = 0; k < 8; ++k) {
        float m = (k == i0 || k == i1) ? 1.f : 0.f;
        msk[t * 8 + k] = m;
        out_mask[t * 8 + k] = m;
      }
    }
    __syncthreads();
    if (t == 0) {
      float aux = 0.f;
#pragma unroll
      for (int k = 0; k < 8; ++k) {
        float mp = 0.f, mm = 0.f;
#pragma unroll
        for (int bb = 0; bb < 8; ++bb) { mp += probs[bb * 8 + k]; mm += msk[bb * 8 + k]; }
        aux += (mp * 0.125f) * (mm * 0.125f);
      }
      out_aux[0] = 8.f * aux;
    }
  }
}

// ---------------------------------------------------------------------------
// Barrier-free per-wave K-loop (AITER-style): wave owns a 64m x 64n tile and
// a private 16 KB LDS region ([A0|A1|B0|B1] x 4KB).  Depth-2 pipeline:
//   wait vmcnt<=8 (oldest tile landed, newest still in flight — NEVER 0)
//   ds_read 8 frags -> wait lgkm(0) -> issue 8 glds16 for kt+2 -> 16 MFMA.
// No __syncthreads anywhere: vmcnt is per-wave, waves never collectively
// drain.  Swizzle S=(m15>>1)&3 -> conflict-free quarter-wave phases.
// ---------------------------------------------------------------------------
__device__ __forceinline__ void kloop_wave(const bf16_t* __restrict__ A,
                                           const bf16_t* __restrict__ Bt,
                                           char* wlds, int lane,
                                           f32x4 acc[4][4]) {
  const int m15 = lane & 15, q = lane >> 4;
  const int srow = lane >> 2;                       // staging row within group
  const int scp  = (lane & 3) ^ ((lane >> 3) & 3);  // chunk = pos ^ S(row)
  const bf16_t* gA[4];
  const bf16_t* gB[4];
#pragma unroll
  for (int i = 0; i < 4; ++i) {
    gA[i] = A  + (size_t)(i * 16 + srow) * DIM + scp * 8;
    gB[i] = Bt + (size_t)(i * 16 + srow) * DIM + scp * 8;
  }
  char* lA = wlds;          // 2 x 4KB
  char* lB = wlds + 8192;   // 2 x 4KB
  const int sw = (q ^ ((m15 >> 1) & 3)) * 16;
  int off_[4];
#pragma unroll
  for (int i = 0; i < 4; ++i) off_[i] = (i * 16 + m15) * 64 + sw;

  // prologue: kt0 -> buf0, kt1 -> buf1 (16 outstanding)
#pragma unroll
  for (int i = 0; i < 4; ++i) {
    glds16(gA[i], lA + i * 1024 + lane * 16);
    glds16(gB[i], lB + i * 1024 + lane * 16);
  }
#pragma unroll
  for (int i = 0; i < 4; ++i) {
    glds16(gA[i] + 32, lA + 4096 + i * 1024 + lane * 16);
    glds16(gB[i] + 32, lB + 4096 + i * 1024 + lane * 16);
  }

#pragma unroll 2
  for (int kt = 0; kt < 30; ++kt) {
    const int buf = (kt & 1) * 4096;
    WAIT_VM8();
    bf16x8 af[4], bfr[4];
#pragma unroll
    for (int i = 0; i < 4; ++i) af[i]  = *(const bf16x8*)(lA + buf + off_[i]);
#pragma unroll
    for (int j = 0; j < 4; ++j) bfr[j] = *(const bf16x8*)(lB + buf + off_[j]);
    WAIT_LGKM();                       // frags in VGPRs; buffer reusable
    const int go = (kt + 2) * 32;
#pragma unroll
    for (int i = 0; i < 4; ++i) {
      glds16(gA[i] + go, lA + buf + i * 1024 + lane * 16);
      glds16(gB[i] + go, lB + buf + i * 1024 + lane * 16);
    }
#pragma unroll
    for (int i = 0; i < 4; ++i)
#pragma unroll
      for (int j = 0; j < 4; ++j)
        acc[i][j] = __builtin_amdgcn_mfma_f32_16x16x32_bf16(af[i], bfr[j], acc[i][j], 0, 0, 0);
  }
  // kt = 30 (buf0): newest 8 = kt31's
  {
    WAIT_VM8();
    bf16x8 af[4], bfr[4];
#pragma unroll
    for (int i = 0; i < 4; ++i) af[i]  = *(const bf16x8*)(lA + off_[i]);
#pragma unroll
    for (int j = 0; j < 4; ++j) bfr[j] = *(const bf16x8*)(lB + off_[j]);
#pragma unroll
    for (int i = 0; i < 4; ++i)
#pragma unroll
      for (int j = 0; j < 4; ++j)
        acc[i][j] = __builtin_amdgcn_mfma_f32_16x16x32_bf16(af[i], bfr[j], acc[i][j], 0, 0, 0);
  }
  // kt = 31 (buf1): must drain fully
  {
    WAIT_VM0();
    bf16x8 af[4], bfr[4];
#pragma unroll
    for (int i = 0; i < 4; ++i) af[i]  = *(const bf16x8*)(lA + 4096 + off_[i]);
#pragma unroll
    for (int j = 0; j < 4; ++j) bfr[j] = *(const bf16x8*)(lB + 4096 + off_[j]);
#pragma unroll
    for (int i = 0; i < 4; ++i)
#pragma unroll
      for (int j = 0; j < 4; ++j)
        acc[i][j] = __builtin_amdgcn_mfma_f32_16x16x32_bf16(af[i], bfr[j], acc[i][j], 0, 0, 0);
  }
}

// ---------------------------------------------------------------------------
// GEMM1: hidden[slot] = topk_w[slot] * relu(x[b] @ w1[e] + b1[e]), bf16.
// grid (8 N, 4 M, 17), 256 thr = 4 waves (2m x 2n), 64 KB LDS, 2 blocks/CU.
// z==16: bias-init slice writes out = w0*b2[e0] + w1*b2[e1].
// ---------------------------------------------------------------------------
__global__ __launch_bounds__(256, 2) void gemm1_kernel(
    const bf16_t* __restrict__ xb, const bf16_t* __restrict__ w1t,
    const float* __restrict__ b1, const float* __restrict__ b2,
    const int* __restrict__ topk_idx, const float* __restrict__ topk_w,
    bf16_t* __restrict__ hidden, float* __restrict__ out) {
  __shared__ __align__(16) char smem[65536];
  const int tid = threadIdx.x;
  const int bN = blockIdx.x, bM = blockIdx.y, slot = blockIdx.z;

  if (slot == 16) {
    const int b = bN;
    const int s0 = bM * 128;
    const float g0 = topk_w[b * 2], g1 = topk_w[b * 2 + 1];
    const float4 v0 = ((const float4*)(b2 + topk_idx[b * 2] * DIM))[tid];
    const float4 v1 = ((const float4*)(b2 + topk_idx[b * 2 + 1] * DIM))[tid];
    float4 bb;
    bb.x = g0 * v0.x + g1 * v1.x;
    bb.y = g0 * v0.y + g1 * v1.y;
    bb.z = g0 * v0.z + g1 * v1.z;
    bb.w = g0 * v0.w + g1 * v1.w;
    float* O = out + (size_t)b * SEQL * DIM;
#pragma unroll 8
    for (int row = 0; row < 128; ++row)
      *(float4*)(O + (size_t)(s0 + row) * DIM + tid * 4) = bb;
    return;
  }

  const int lane = tid & 63, w = tid >> 6;
  const int wm = w & 1, wn = w >> 1;
  char* wlds = smem + w * 16384;
  const int b = slot >> 1;
  const int e = topk_idx[slot];
  const float gw = topk_w[slot];

  const bf16_t* A  = xb + ((size_t)b * SEQL + bM * 128 + wm * 64) * DIM;
  const bf16_t* Bt = w1t + ((size_t)e * DIM + bN * 128 + wn * 64) * DIM;

  f32x4 acc[4][4];
#pragma unroll
  for (int i = 0; i < 4; ++i)
#pragma unroll
    for (int j = 0; j < 4; ++j) acc[i][j] = {0.f, 0.f, 0.f, 0.f};

  kloop_wave(A, Bt, wlds, lane, acc);

  // wave-private epilogue: bias+relu+gate+cast via LDS bounce (stride 72 hw).
  // C/D layout: col = lane&15, row = quad*4+reg (m89-verified).
  const int m15 = lane & 15, q = lane >> 4;
  const float* be = b1 + e * DIM + bN * 128 + wn * 64;
  bf16_t* hb = (bf16_t*)wlds;
#pragma unroll
  for (int j = 0; j < 4; ++j) {
    const float bias = be[j * 16 + m15];
#pragma unroll
    for (int i = 0; i < 4; ++i)
#pragma unroll
      for (int r = 0; r < 4; ++r)
        hb[(i * 16 + q * 4 + r) * 72 + j * 16 + m15] =
            (bf16_t)(gw * fmaxf(acc[i][j][r] + bias, 0.f));
  }
  CFENCE();
  bf16_t* H = hidden + (size_t)slot * SEQL * DIM +
              ((size_t)(bM * 128 + wm * 64)) * DIM + bN * 128 + wn * 64;
#pragma unroll
  for (int it = 0; it < 8; ++it) {
    const int idx = it * 64 + lane;
    const int row = idx >> 3, ch = idx & 7;
    *(bf16x8*)(H + (size_t)row * DIM + ch * 8) = *(const bf16x8*)(hb + row * 72 + ch * 8);
  }
}

// ---------------------------------------------------------------------------
// GEMM2: out += h[slot] @ w2[e_slot] (hidden pre-gated; bias pre-written).
// grid (8 N, 4 M, 16 slots), 256 thr = 4 waves, 64 KB LDS, atomicAdd combine.
// ---------------------------------------------------------------------------
__global__ __launch_bounds__(256, 2) void gemm2_kernel(
    const bf16_t* __restrict__ hidden, const bf16_t* __restrict__ w2t,
    const int* __restrict__ topk_idx, float* __restrict__ out) {
  __shared__ __align__(16) char smem[65536];
  const int tid = threadIdx.x;
  const int bN = blockIdx.x, bM = blockIdx.y, slot = blockIdx.z;
  const int lane = tid & 63, w = tid >> 6;
  const int wm = w & 1, wn = w >> 1;
  char* wlds = smem + w * 16384;
  const int b = slot >> 1;
  const int e = topk_idx[slot];

  const bf16_t* A  = hidden + ((size_t)slot * SEQL + bM * 128 + wm * 64) * DIM;
  const bf16_t* Bt = w2t + ((size_t)e * DIM + bN * 128 + wn * 64) * DIM;

  f32x4 acc[4][4];
#pragma unroll
  for (int i = 0; i < 4; ++i)
#pragma unroll
    for (int j = 0; j < 4; ++j) acc[i][j] = {0.f, 0.f, 0.f, 0.f};

  kloop_wave(A, Bt, wlds, lane, acc);

  const int m15 = lane & 15, q = lane >> 4;
  float* O = out + (size_t)b * SEQL * DIM;
#pragma unroll
  for (int i = 0; i < 4; ++i) {
    const int row = bM * 128 + wm * 64 + i * 16 + q * 4;
#pragma unroll
    for (int j = 0; j < 4; ++j) {
      const int col = bN * 128 + wn * 64 + j * 16 + m15;
#pragma unroll
      for (int r = 0; r < 4; ++r)
        atomicAdd(&O[(size_t)(row + r) * DIM + col], acc[i][j][r]);
    }
  }
}

// ---------------------------------------------------------------------------
extern "C" void kernel_launch(void* const* d_in, const int* in_sizes, int n_in,
                              void* d_out, int out_size, void* d_ws, size_t ws_size,
                              hipStream_t stream) {
  const float* x   = (const float*)d_in[0];
  const float* dec = (const float*)d_in[1];
  const float* rw  = (const float*)d_in[2];
  const float* rb  = (const float*)d_in[3];
  const float* w1  = (const float*)d_in[4];
  const float* w2  = (const float*)d_in[5];
  const float* b1  = (const float*)d_in[6];
  const float* b2  = (const float*)d_in[7];
  float* out = (float*)d_out;

  // ws layout: xb 8MB | w1t 16MB | w2t 16MB | hidden 16MB | router scratch
  char* ws = (char*)d_ws;
  bf16_t* xb   = (bf16_t*)(ws);
  bf16_t* w1t  = (bf16_t*)(ws + (8u << 20));
  bf16_t* w2t  = (bf16_t*)(ws + (24u << 20));
  bf16_t* hid  = (bf16_t*)(ws + (40u << 20));
  int*    idxw = (int*)(ws + (56u << 20));
  float*  ww   = (float*)(ws + (56u << 20) + 64);

  hipLaunchKernelGGL(prep_kernel, dim3(4096 + 512 + 1), dim3(256), 0, stream,
                     x, dec, rw, rb, w1, w2, xb, w1t, w2t,
                     out + OFF_AUX, out + OFF_MASK, out + OFF_LOGITS, idxw, ww);
  hipLaunchKernelGGL(gemm1_kernel, dim3(8, 4, 17), dim3(256), 0, stream,
                     xb, w1t, b1, b2, idxw, ww, hid, out);
  hipLaunchKernelGGL(gemm2_kernel, dim3(8, 4, 16), dim3(256), 0, stream,
                     hid, w2t, idxw, out);
}